// Round 2
// baseline (610.629 us; speedup 1.0000x reference)
//
#include <hip/hip_runtime.h>
#include <stdint.h>

#define FEAT_STRIDE 16
#define PRE_NMS 6000
#define POST_NMS 300
#define NMS_TH 0.7f

static constexpr int B_ = 2, A_ = 9, H_ = 32, W_ = 32, T_ = 16;
static constexpr int LOC = H_ * W_ * T_;   // 16384
static constexpr int N_ = LOC * A_;        // 147456
static constexpr int NBIN = 65536;
static constexpr int CAP = 8192;           // candidate capacity per batch
static constexpr int NW = 94;              // ceil(6000/64) mask words per row
static constexpr int ROWS = 6016;          // NW*64 padded rows

// ---- float <-> monotonic u32 key ----
__device__ __forceinline__ uint32_t f2u(float f) {
    uint32_t b = __float_as_uint(f);
    return b ^ ((b >> 31) ? 0xFFFFFFFFu : 0x80000000u);
}
__device__ __forceinline__ float u2f(uint32_t u) {
    uint32_t b = (u >> 31) ? (u ^ 0x80000000u) : ~u;
    return __uint_as_float(b);
}

// 1) histogram of score keys' top-16 bits (coalesced: loc innermost)
__global__ void hist_kernel(const float* __restrict__ scores_map,
                            unsigned int* __restrict__ hist) {
    int gid = blockIdx.x * blockDim.x + threadIdx.x;
    if (gid >= B_ * N_) return;
    int b = gid / N_;
    int r = gid - b * N_;
    int a = r / LOC;
    int loc = r - a * LOC;
    float sc = scores_map[((size_t)(b * 2 * A_ + A_ + a)) * LOC + loc];
    uint32_t u = f2u(sc);
    atomicAdd(&hist[b * NBIN + (u >> 16)], 1u);
}

// 2) per batch: find histogram bin where cumulative-from-top crosses PRE_NMS
__global__ void scan_kernel(const unsigned int* __restrict__ hist,
                            unsigned int* __restrict__ thr) {
    int bb = blockIdx.x;
    int t = threadIdx.x;                 // 1024 threads
    __shared__ unsigned int ssum[1024];
    const unsigned int* h = hist + (size_t)bb * NBIN;
    int base = t * 64;
    const uint4* h4 = reinterpret_cast<const uint4*>(h + base);
    unsigned int s = 0;
#pragma unroll
    for (int q = 0; q < 16; ++q) {
        uint4 v = h4[q];
        s += v.x + v.y + v.z + v.w;
    }
    ssum[t] = s;
    __syncthreads();
    for (int off = 1; off < 1024; off <<= 1) {
        unsigned int v = (t + off < 1024) ? ssum[t + off] : 0u;
        __syncthreads();
        ssum[t] += v;
        __syncthreads();
    }
    unsigned int excl = (t < 1023) ? ssum[t + 1] : 0u;
    if (excl < (unsigned)PRE_NMS && excl + s >= (unsigned)PRE_NMS) {
        unsigned int run = excl;
        for (int q = 63; q >= 0; --q) {
            run += h[base + q];
            if (run >= (unsigned)PRE_NMS) {
                thr[bb * 2 + 0] = (unsigned)(base + q);
                thr[bb * 2 + 1] = run;
                break;
            }
        }
    }
}

// 3) compact all keys whose top-16 bits >= threshold bin (coalesced reads)
__global__ void compact_kernel(const float* __restrict__ scores_map,
                               const unsigned int* __restrict__ thr,
                               unsigned long long* __restrict__ cand,
                               unsigned int* __restrict__ cnt) {
    int gid = blockIdx.x * blockDim.x + threadIdx.x;
    if (gid >= B_ * N_) return;
    int b = gid / N_;
    int r = gid - b * N_;
    int a = r / LOC;
    int loc = r - a * LOC;
    float sc = scores_map[((size_t)(b * 2 * A_ + A_ + a)) * LOC + loc];
    uint32_t u = f2u(sc);
    if ((u >> 16) >= thr[b * 2]) {
        int n = loc * A_ + a;   // reference flat index
        unsigned long long key = ((unsigned long long)u << 18)
                               | (unsigned long long)(N_ - 1 - n);
        unsigned int p = atomicAdd(&cnt[b], 1u);
        if (p < (unsigned)CAP) cand[(size_t)b * CAP + p] = key;
    }
}

// 4) per batch: bitonic sort (descending) of candidates in LDS, keep top PRE_NMS
__global__ void __launch_bounds__(1024) sort_kernel(unsigned long long* __restrict__ cand,
                                                    const unsigned int* __restrict__ cnt) {
    __shared__ unsigned long long sk[CAP];   // 64 KiB
    int bb = blockIdx.x, t = threadIdx.x;
    unsigned int c = cnt[bb];
    if (c > (unsigned)CAP) c = CAP;
    for (int idx = t; idx < CAP; idx += 1024)
        sk[idx] = (idx < (int)c) ? cand[(size_t)bb * CAP + idx] : 0ull;
    __syncthreads();
    for (int k = 2; k <= CAP; k <<= 1) {
        for (int j = k >> 1; j > 0; j >>= 1) {
            for (int idx = t; idx < CAP; idx += 1024) {
                int ixj = idx ^ j;
                if (ixj > idx) {
                    bool desc = ((idx & k) == 0);
                    unsigned long long a = sk[idx], bv = sk[ixj];
                    if (desc ? (a < bv) : (a > bv)) { sk[idx] = bv; sk[ixj] = a; }
                }
            }
            __syncthreads();
        }
    }
    for (int idx = t; idx < PRE_NMS; idx += 1024)
        cand[(size_t)bb * CAP + idx] = sk[idx];
}

// 5) decode boxes for the 6000 sorted candidates only
//    sortedBox row: [score, x1,y1,z1, x2,y2,z2, vol]
__global__ void gather_decode(const unsigned long long* __restrict__ cand,
                              const float* __restrict__ bbox_frame,
                              const float* __restrict__ im_info,
                              const float* __restrict__ anchors,
                              float* __restrict__ sortedBox) {
    int s = blockIdx.x * blockDim.x + threadIdx.x;
    if (s >= B_ * PRE_NMS) return;
    int bb = s / PRE_NMS;
    int r = s - bb * PRE_NMS;
    unsigned long long key = cand[(size_t)bb * CAP + r];
    uint32_t u = (uint32_t)(key >> 18);
    int n = N_ - 1 - (int)(key & 0x3FFFFull);
    int a = n % A_;
    int loc = n / A_;
    int k = loc % T_;
    int j = (loc / T_) % W_;
    int i = loc / (T_ * W_);

    float ax1 = anchors[a * 6 + 0] + (float)(FEAT_STRIDE * j);
    float ay1 = anchors[a * 6 + 1] + (float)(FEAT_STRIDE * i);
    float az1 = anchors[a * 6 + 2] + (float)k;
    float ax2 = anchors[a * 6 + 3] + (float)(FEAT_STRIDE * j);
    float ay2 = anchors[a * 6 + 4] + (float)(FEAT_STRIDE * i);
    float az2 = anchors[a * 6 + 5] + (float)k;
    float aw = ax2 - ax1 + 1.0f, ah = ay2 - ay1 + 1.0f, al = az2 - az1 + 1.0f;
    float acx = ax1 + 0.5f * aw, acy = ay1 + 0.5f * ah, acz = az1 + 0.5f * al;

    const float* dp = bbox_frame + ((size_t)(bb * 6 * A_ + a * 6)) * LOC
                    + i * (W_ * T_) + j * T_ + k;
    float d0 = dp[0 * LOC], d1 = dp[1 * LOC], d2 = dp[2 * LOC];
    float d3 = dp[3 * LOC], d4 = dp[4 * LOC], d5 = dp[5 * LOC];

    float pcx = d0 * aw + acx, pcy = d1 * ah + acy, pcz = d2 * al + acz;
    float pw = expf(d3) * aw, ph = expf(d4) * ah, pl = expf(d5) * al;

    float x1 = pcx - 0.5f * pw, y1 = pcy - 0.5f * ph, z1 = pcz - 0.5f * pl;
    float x2 = pcx + 0.5f * pw, y2 = pcy + 0.5f * ph, z2 = pcz + 0.5f * pl;

    float lx = im_info[1] - 1.0f, ly = im_info[0] - 1.0f, lz = im_info[2] - 1.0f;
    x1 = fminf(fmaxf(x1, 0.0f), lx); y1 = fminf(fmaxf(y1, 0.0f), ly); z1 = fminf(fmaxf(z1, 0.0f), lz);
    x2 = fminf(fmaxf(x2, 0.0f), lx); y2 = fminf(fmaxf(y2, 0.0f), ly); z2 = fminf(fmaxf(z2, 0.0f), lz);

    float vol = (x2 - x1 + 1.0f) * (y2 - y1 + 1.0f) * (z2 - z1 + 1.0f);
    float* p = sortedBox + ((size_t)bb * ROWS + r) * 8;
    p[0] = u2f(u);
    p[1] = x1; p[2] = y1; p[3] = z1;
    p[4] = x2; p[5] = y2; p[6] = z2;
    p[7] = vol;
}

// 6) IoU bitmask: mask[bb][i][w] bit b = (j=64w+b > i) && IoU(i,j) > TH
__global__ void mask_build(const float* __restrict__ sortedBox,
                           unsigned long long* __restrict__ mask) {
    int g = blockIdx.x / NW, w = blockIdx.x % NW;
    if (w < g) return;                      // only need upper triangle words
    int bb = blockIdx.y;
    int lane = threadIdx.x;                 // 64 threads
    __shared__ float colb[64][7];           // x1,y1,z1,x2,y2,z2,vol
    const float* sb = sortedBox + (size_t)bb * ROWS * 8;
    int col = w * 64 + lane;
    if (col < PRE_NMS) {
        const float* cp = sb + (size_t)col * 8;
        colb[lane][0] = cp[1]; colb[lane][1] = cp[2]; colb[lane][2] = cp[3];
        colb[lane][3] = cp[4]; colb[lane][4] = cp[5]; colb[lane][5] = cp[6];
        colb[lane][6] = cp[7];
    } else {
        colb[lane][0] = 3e8f; colb[lane][1] = 0.f; colb[lane][2] = 0.f;
        colb[lane][3] = -3e8f; colb[lane][4] = 0.f; colb[lane][5] = 0.f;
        colb[lane][6] = 1.0f;
    }
    __syncthreads();
    int row = g * 64 + lane;
    if (row >= PRE_NMS) return;
    const float* rp = sb + (size_t)row * 8;
    float x1 = rp[1], y1 = rp[2], z1 = rp[3];
    float x2 = rp[4], y2 = rp[5], z2 = rp[6], v = rp[7];
    unsigned long long word = 0;
    for (int b2 = 0; b2 < 64; ++b2) {
        float iw = fminf(x2, colb[b2][3]) - fmaxf(x1, colb[b2][0]) + 1.0f;
        float ih = fminf(y2, colb[b2][4]) - fmaxf(y1, colb[b2][1]) + 1.0f;
        float il = fminf(z2, colb[b2][5]) - fmaxf(z1, colb[b2][2]) + 1.0f;
        iw = fmaxf(iw, 0.0f); ih = fmaxf(ih, 0.0f); il = fmaxf(il, 0.0f);
        float inter = iw * ih * il;
        float iou = inter / (v + colb[b2][6] - inter);
        int cidx = w * 64 + b2;
        if (cidx > row && iou > NMS_TH) word |= (1ull << b2);
    }
    mask[((size_t)bb * ROWS + row) * NW + w] = word;
}

// 7) serial greedy suppress over the bitmask (one wave per batch), early exit at 300
__global__ void suppress_kernel(const unsigned long long* __restrict__ mask,
                                const float* __restrict__ sortedBox,
                                float* __restrict__ out) {
    int bb = blockIdx.x;
    int lane = threadIdx.x;                 // 64 threads = 1 wave
    __shared__ unsigned long long remv[NW];
    __shared__ int keptRows[64];
    for (int i = lane; i < NW; i += 64) remv[i] = 0ull;
    if (lane == 0) remv[NW - 1] = ~((1ull << (PRE_NMS - (NW - 1) * 64)) - 1ull);
    __syncthreads();

    const unsigned long long* M = mask + (size_t)bb * ROWS * NW;
    const float* sb = sortedBox + (size_t)bb * ROWS * 8;
    float* ob = out + (size_t)bb * POST_NMS * 7;

    int kept = 0;
    unsigned long long diag = M[(size_t)lane * NW + 0];   // chunk 0 diagonal
    for (int c = 0; c < NW && kept < POST_NMS; ++c) {
        unsigned long long w = remv[c];
        unsigned long long diag_next = (c + 1 < NW)
            ? M[(size_t)((c + 1) * 64 + lane) * NW + (c + 1)] : 0ull;
        unsigned long long keptbits = 0;
        unsigned long long m = ~w;
        int nk = 0;
        while (m && (kept + nk) < POST_NMS) {
            int b = __builtin_ctzll(m);
            m &= m - 1;
            if ((w >> b) & 1ull) continue;
            keptbits |= (1ull << b);
            if (lane == 0) keptRows[nk] = c * 64 + b;
            ++nk;
            w |= __shfl(diag, b);
        }
        __syncthreads();   // publish keptRows
        // OR kept rows into remv for future words (coalesced across lanes)
        unsigned long long kb = keptbits;
        while (kb) {
            int b = __builtin_ctzll(kb);
            kb &= kb - 1;
            int rrow = c * 64 + b;
            for (int w2 = c + 1 + lane; w2 < NW; w2 += 64)
                remv[w2] |= M[(size_t)rrow * NW + w2];
        }
        // write output rows for this chunk's kept candidates
        {
            int i = lane >> 3, j = lane & 7;
            for (; i < nk; i += 8)
                if (j < 7)
                    ob[(size_t)(kept + i) * 7 + j] = sb[(size_t)keptRows[i] * 8 + j];
        }
        kept += nk;
        diag = diag_next;
        __syncthreads();
    }
    __syncthreads();
    for (int idx = kept * 7 + lane; idx < POST_NMS * 7; idx += 64)
        ob[idx] = 0.0f;
}

extern "C" void kernel_launch(void* const* d_in, const int* in_sizes, int n_in,
                              void* d_out, int out_size, void* d_ws, size_t ws_size,
                              hipStream_t stream) {
    const float* scores_map = (const float*)d_in[0];
    const float* bbox_frame = (const float*)d_in[1];
    const float* im_info    = (const float*)d_in[2];
    const float* anchors    = (const float*)d_in[3];
    float* out = (float*)d_out;

    // workspace layout (bytes), total ~10.09 MB (fits proven ws)
    char* ws = (char*)d_ws;
    unsigned long long* cand = (unsigned long long*)(ws + 0);          // 131072
    unsigned long long* mask = (unsigned long long*)(ws + 131072);     // 9,048,064
    float* sortedBox         = (float*)(ws + 9179136);                 // 385,024
    unsigned int* hist       = (unsigned int*)(ws + 9564160);          // 524,288
    unsigned int* cnt        = (unsigned int*)(ws + 10088448);         // 8
    unsigned int* thr        = (unsigned int*)(ws + 10088456);         // 16

    hipMemsetAsync(hist, 0, 524288 + 8, stream);   // hist + cnt

    int total = B_ * N_;
    hist_kernel<<<(total + 255) / 256, 256, 0, stream>>>(scores_map, hist);
    scan_kernel<<<B_, 1024, 0, stream>>>(hist, thr);
    compact_kernel<<<(total + 255) / 256, 256, 0, stream>>>(scores_map, thr, cand, cnt);
    sort_kernel<<<B_, 1024, 0, stream>>>(cand, cnt);
    gather_decode<<<(B_ * PRE_NMS + 255) / 256, 256, 0, stream>>>(cand, bbox_frame,
                                                                  im_info, anchors, sortedBox);
    mask_build<<<dim3(NW * NW, B_), 64, 0, stream>>>(sortedBox, mask);
    suppress_kernel<<<B_, 64, 0, stream>>>(mask, sortedBox, out);
}

// Round 3
// 446.760 us; speedup vs baseline: 1.3668x; 1.3668x over previous
//
#include <hip/hip_runtime.h>
#include <stdint.h>

#define FEAT_STRIDE 16
#define PRE_NMS 6000
#define POST_NMS 300
#define NMS_TH 0.7f

static constexpr int B_ = 2, A_ = 9, H_ = 32, W_ = 32, T_ = 16;
static constexpr int LOC = H_ * W_ * T_;   // 16384
static constexpr int N_ = LOC * A_;        // 147456
static constexpr int NBIN = 65536;
static constexpr int CAP = 8192;           // candidate capacity per batch
static constexpr int NW = 94;              // ceil(6000/64) mask words per row
static constexpr int ROWS = 6016;          // NW*64 padded rows

// ---- float <-> monotonic u32 key ----
__device__ __forceinline__ uint32_t f2u(float f) {
    uint32_t b = __float_as_uint(f);
    return b ^ ((b >> 31) ? 0xFFFFFFFFu : 0x80000000u);
}
__device__ __forceinline__ float u2f(uint32_t u) {
    uint32_t b = (u >> 31) ? (u ^ 0x80000000u) : ~u;
    return __uint_as_float(b);
}

// 1) histogram of score keys' top-16 bits (coalesced: loc innermost)
__global__ void hist_kernel(const float* __restrict__ scores_map,
                            unsigned int* __restrict__ hist) {
    int gid = blockIdx.x * blockDim.x + threadIdx.x;
    if (gid >= B_ * N_) return;
    int b = gid / N_;
    int r = gid - b * N_;
    int a = r / LOC;
    int loc = r - a * LOC;
    float sc = scores_map[((size_t)(b * 2 * A_ + A_ + a)) * LOC + loc];
    uint32_t u = f2u(sc);
    atomicAdd(&hist[b * NBIN + (u >> 16)], 1u);
}

// 2) per batch: find histogram bin where cumulative-from-top crosses PRE_NMS
__global__ void scan_kernel(const unsigned int* __restrict__ hist,
                            unsigned int* __restrict__ thr) {
    int bb = blockIdx.x;
    int t = threadIdx.x;                 // 1024 threads
    __shared__ unsigned int ssum[1024];
    const unsigned int* h = hist + (size_t)bb * NBIN;
    int base = t * 64;
    const uint4* h4 = reinterpret_cast<const uint4*>(h + base);
    unsigned int s = 0;
#pragma unroll
    for (int q = 0; q < 16; ++q) {
        uint4 v = h4[q];
        s += v.x + v.y + v.z + v.w;
    }
    ssum[t] = s;
    __syncthreads();
    for (int off = 1; off < 1024; off <<= 1) {
        unsigned int v = (t + off < 1024) ? ssum[t + off] : 0u;
        __syncthreads();
        ssum[t] += v;
        __syncthreads();
    }
    unsigned int excl = (t < 1023) ? ssum[t + 1] : 0u;
    if (excl < (unsigned)PRE_NMS && excl + s >= (unsigned)PRE_NMS) {
        unsigned int run = excl;
        for (int q = 63; q >= 0; --q) {
            run += h[base + q];
            if (run >= (unsigned)PRE_NMS) {
                thr[bb * 2 + 0] = (unsigned)(base + q);
                thr[bb * 2 + 1] = run;
                break;
            }
        }
    }
}

// 3) compact all keys whose top-16 bits >= threshold bin (coalesced reads)
__global__ void compact_kernel(const float* __restrict__ scores_map,
                               const unsigned int* __restrict__ thr,
                               unsigned long long* __restrict__ cand,
                               unsigned int* __restrict__ cnt) {
    int gid = blockIdx.x * blockDim.x + threadIdx.x;
    if (gid >= B_ * N_) return;
    int b = gid / N_;
    int r = gid - b * N_;
    int a = r / LOC;
    int loc = r - a * LOC;
    float sc = scores_map[((size_t)(b * 2 * A_ + A_ + a)) * LOC + loc];
    uint32_t u = f2u(sc);
    if ((u >> 16) >= thr[b * 2]) {
        int n = loc * A_ + a;   // reference flat index
        unsigned long long key = ((unsigned long long)u << 18)
                               | (unsigned long long)(N_ - 1 - n);
        unsigned int p = atomicAdd(&cnt[b], 1u);
        if (p < (unsigned)CAP) cand[(size_t)b * CAP + p] = key;
    }
}

// 4) rank-sort + decode: each candidate computes its exact rank (keys unique),
//    then decodes its box straight into sortedBox[rank].
//    sortedBox row: [score, x1,y1,z1, x2,y2,z2, vol]
__global__ void __launch_bounds__(1024) rank_decode(
        const unsigned long long* __restrict__ cand,
        const unsigned int* __restrict__ cnt,
        const float* __restrict__ bbox_frame,
        const float* __restrict__ im_info,
        const float* __restrict__ anchors,
        float* __restrict__ sortedBox) {
    __shared__ __align__(16) unsigned long long keys[CAP];   // 64 KiB
    int bb = blockIdx.y;
    int tid = threadIdx.x;
    int count = (int)cnt[bb];
    if (count > CAP) count = CAP;
    for (int i = tid; i < CAP; i += 1024)
        keys[i] = (i < count) ? cand[(size_t)bb * CAP + i] : 0ull;
    __syncthreads();
    int i = blockIdx.x * 1024 + tid;
    if (i >= count) return;
    unsigned long long me = keys[i];
    int rank = 0;
    const ulonglong2* k2 = reinterpret_cast<const ulonglong2*>(keys);
    int c2 = count >> 1;
    for (int j2 = 0; j2 < c2; ++j2) {
        ulonglong2 v = k2[j2];              // broadcast LDS read (same addr all lanes)
        rank += (v.x > me) + (v.y > me);
    }
    if (count & 1) rank += (keys[count - 1] > me);
    if (rank >= PRE_NMS) return;

    uint32_t u = (uint32_t)(me >> 18);
    int n = N_ - 1 - (int)(me & 0x3FFFFull);
    int a = n % A_;
    int loc = n / A_;
    int k = loc % T_;
    int j = (loc / T_) % W_;
    int ii = loc / (T_ * W_);

    float ax1 = anchors[a * 6 + 0] + (float)(FEAT_STRIDE * j);
    float ay1 = anchors[a * 6 + 1] + (float)(FEAT_STRIDE * ii);
    float az1 = anchors[a * 6 + 2] + (float)k;
    float ax2 = anchors[a * 6 + 3] + (float)(FEAT_STRIDE * j);
    float ay2 = anchors[a * 6 + 4] + (float)(FEAT_STRIDE * ii);
    float az2 = anchors[a * 6 + 5] + (float)k;
    float aw = ax2 - ax1 + 1.0f, ah = ay2 - ay1 + 1.0f, al = az2 - az1 + 1.0f;
    float acx = ax1 + 0.5f * aw, acy = ay1 + 0.5f * ah, acz = az1 + 0.5f * al;

    const float* dp = bbox_frame + ((size_t)(bb * 6 * A_ + a * 6)) * LOC
                    + ii * (W_ * T_) + j * T_ + k;
    float d0 = dp[0 * LOC], d1 = dp[1 * LOC], d2 = dp[2 * LOC];
    float d3 = dp[3 * LOC], d4 = dp[4 * LOC], d5 = dp[5 * LOC];

    float pcx = d0 * aw + acx, pcy = d1 * ah + acy, pcz = d2 * al + acz;
    float pw = expf(d3) * aw, ph = expf(d4) * ah, pl = expf(d5) * al;

    float x1 = pcx - 0.5f * pw, y1 = pcy - 0.5f * ph, z1 = pcz - 0.5f * pl;
    float x2 = pcx + 0.5f * pw, y2 = pcy + 0.5f * ph, z2 = pcz + 0.5f * pl;

    float lx = im_info[1] - 1.0f, ly = im_info[0] - 1.0f, lz = im_info[2] - 1.0f;
    x1 = fminf(fmaxf(x1, 0.0f), lx); y1 = fminf(fmaxf(y1, 0.0f), ly); z1 = fminf(fmaxf(z1, 0.0f), lz);
    x2 = fminf(fmaxf(x2, 0.0f), lx); y2 = fminf(fmaxf(y2, 0.0f), ly); z2 = fminf(fmaxf(z2, 0.0f), lz);

    float vol = (x2 - x1 + 1.0f) * (y2 - y1 + 1.0f) * (z2 - z1 + 1.0f);
    float* p = sortedBox + ((size_t)bb * ROWS + rank) * 8;
    p[0] = u2f(u);
    p[1] = x1; p[2] = y1; p[3] = z1;
    p[4] = x2; p[5] = y2; p[6] = z2;
    p[7] = vol;
}

// 5) IoU bitmask: mask[bb][i][w] bit b = (j=64w+b > i) && IoU(i,j) > TH
//    diagonal blocks (w==g) additionally store their word to diagArr[row] (coalesced
//    consumption in suppress).
__global__ void mask_build(const float* __restrict__ sortedBox,
                           unsigned long long* __restrict__ mask,
                           unsigned long long* __restrict__ diagArr) {
    int g = blockIdx.x / NW, w = blockIdx.x % NW;
    if (w < g) return;                      // only need upper triangle words
    int bb = blockIdx.y;
    int lane = threadIdx.x;                 // 64 threads
    __shared__ float colb[64][7];           // x1,y1,z1,x2,y2,z2,vol
    const float* sb = sortedBox + (size_t)bb * ROWS * 8;
    int col = w * 64 + lane;
    if (col < PRE_NMS) {
        const float* cp = sb + (size_t)col * 8;
        colb[lane][0] = cp[1]; colb[lane][1] = cp[2]; colb[lane][2] = cp[3];
        colb[lane][3] = cp[4]; colb[lane][4] = cp[5]; colb[lane][5] = cp[6];
        colb[lane][6] = cp[7];
    } else {
        colb[lane][0] = 3e8f; colb[lane][1] = 0.f; colb[lane][2] = 0.f;
        colb[lane][3] = -3e8f; colb[lane][4] = 0.f; colb[lane][5] = 0.f;
        colb[lane][6] = 1.0f;
    }
    __syncthreads();
    int row = g * 64 + lane;
    if (row >= PRE_NMS) return;
    const float* rp = sb + (size_t)row * 8;
    float x1 = rp[1], y1 = rp[2], z1 = rp[3];
    float x2 = rp[4], y2 = rp[5], z2 = rp[6], v = rp[7];
    unsigned long long word = 0;
    for (int b2 = 0; b2 < 64; ++b2) {
        float iw = fminf(x2, colb[b2][3]) - fmaxf(x1, colb[b2][0]) + 1.0f;
        float ih = fminf(y2, colb[b2][4]) - fmaxf(y1, colb[b2][1]) + 1.0f;
        float il = fminf(z2, colb[b2][5]) - fmaxf(z1, colb[b2][2]) + 1.0f;
        iw = fmaxf(iw, 0.0f); ih = fmaxf(ih, 0.0f); il = fmaxf(il, 0.0f);
        float inter = iw * ih * il;
        float iou = inter / (v + colb[b2][6] - inter);
        int cidx = w * 64 + b2;
        if (cidx > row && iou > NMS_TH) word |= (1ull << b2);
    }
    mask[((size_t)bb * ROWS + row) * NW + w] = word;
    if (w == g) diagArr[(size_t)bb * ROWS + row] = word;
}

// 6) greedy suppress: wave0 scans survivors only (serial steps ~= kept count);
//    all 16 waves parallelize the kept-row mask ORs (one round-trip per chunk).
__global__ void __launch_bounds__(1024) suppress_kernel(
        const unsigned long long* __restrict__ mask,
        const unsigned long long* __restrict__ diagArr,
        const float* __restrict__ sortedBox,
        float* __restrict__ out) {
    int bb = blockIdx.x;
    int tid = threadIdx.x;
    int lane = tid & 63, wave = tid >> 6;
    __shared__ unsigned long long remv[NW];
    __shared__ int keptRows[64];
    __shared__ int s_nk;
    for (int i = tid; i < NW; i += 1024) remv[i] = 0ull;
    if (tid == 0) remv[NW - 1] = ~((1ull << (PRE_NMS - (NW - 1) * 64)) - 1ull);
    __syncthreads();

    const unsigned long long* M = mask + (size_t)bb * ROWS * NW;
    const unsigned long long* D = diagArr + (size_t)bb * ROWS;
    const float* sb = sortedBox + (size_t)bb * ROWS * 8;
    float* ob = out + (size_t)bb * POST_NMS * 7;

    int kept_total = 0;
    for (int c = 0; c < NW; ++c) {
        if (wave == 0) {
            unsigned long long diag = D[c * 64 + lane];        // coalesced 512B
            unsigned long long alive = ~remv[c];
            int nk = 0;
            while (alive && (kept_total + nk) < POST_NMS) {
                int b = __builtin_ctzll(alive);
                if (lane == 0) keptRows[nk] = c * 64 + b;
                ++nk;
                unsigned long long d = __shfl(diag, b);
                alive &= ~(d | (1ull << b));
            }
            if (lane == 0) s_nk = nk;
        }
        __syncthreads();
        int nk = s_nk;
        // parallel OR of kept rows into remv words > c (thread per word, loads ILP)
        for (int w2 = c + 1 + tid; w2 < NW; w2 += 1024) {
            unsigned long long v = remv[w2];
            for (int i = 0; i < nk; ++i)
                v |= M[(size_t)keptRows[i] * NW + w2];
            remv[w2] = v;
        }
        // write output rows for this chunk's kept candidates
        for (int e = tid; e < nk * 7; e += 1024) {
            int i = e / 7, j = e - i * 7;
            ob[(size_t)(kept_total + i) * 7 + j] = sb[(size_t)keptRows[i] * 8 + j];
        }
        kept_total += nk;
        __syncthreads();      // remv/keptRows stable before next scan
        if (kept_total >= POST_NMS) break;
    }
    // zero-fill remaining rows
    for (int idx = kept_total * 7 + tid; idx < POST_NMS * 7; idx += 1024)
        ob[idx] = 0.0f;
}

extern "C" void kernel_launch(void* const* d_in, const int* in_sizes, int n_in,
                              void* d_out, int out_size, void* d_ws, size_t ws_size,
                              hipStream_t stream) {
    const float* scores_map = (const float*)d_in[0];
    const float* bbox_frame = (const float*)d_in[1];
    const float* im_info    = (const float*)d_in[2];
    const float* anchors    = (const float*)d_in[3];
    float* out = (float*)d_out;

    // workspace layout (bytes) — same 10.09 MB footprint as the passing round 2
    char* ws = (char*)d_ws;
    unsigned long long* cand    = (unsigned long long*)(ws + 0);          // 131,072
    unsigned long long* mask    = (unsigned long long*)(ws + 131072);     // 9,048,064
    float* sortedBox            = (float*)(ws + 9179136);                 // 385,024
    unsigned int* hist          = (unsigned int*)(ws + 9564160);          // 524,288
    unsigned long long* diagArr = (unsigned long long*)(ws + 9564160);    // aliases hist
                                                                          // (hist dead after scan; diagArr written later) 96,256
    unsigned int* cnt           = (unsigned int*)(ws + 10088448);         // 8
    unsigned int* thr           = (unsigned int*)(ws + 10088456);         // 16

    hipMemsetAsync(hist, 0, 524288 + 8, stream);   // hist + cnt

    int total = B_ * N_;
    hist_kernel<<<(total + 255) / 256, 256, 0, stream>>>(scores_map, hist);
    scan_kernel<<<B_, 1024, 0, stream>>>(hist, thr);
    compact_kernel<<<(total + 255) / 256, 256, 0, stream>>>(scores_map, thr, cand, cnt);
    rank_decode<<<dim3(CAP / 1024, B_), 1024, 0, stream>>>(cand, cnt, bbox_frame,
                                                           im_info, anchors, sortedBox);
    mask_build<<<dim3(NW * NW, B_), 64, 0, stream>>>(sortedBox, mask, diagArr);
    suppress_kernel<<<B_, 1024, 0, stream>>>(mask, diagArr, sortedBox, out);
}

// Round 4
// 306.420 us; speedup vs baseline: 1.9928x; 1.4580x over previous
//
#include <hip/hip_runtime.h>
#include <stdint.h>

#define FEAT_STRIDE 16
#define PRE_NMS 6000
#define POST_NMS 300
#define NMS_TH 0.7f

static constexpr int B_ = 2, A_ = 9, H_ = 32, W_ = 32, T_ = 16;
static constexpr int LOC = H_ * W_ * T_;   // 16384
static constexpr int N_ = LOC * A_;        // 147456
static constexpr int NBIN = 65536;
static constexpr int CAP = 8192;           // candidate capacity per batch
static constexpr int NW = 94;              // ceil(6000/64) mask words per row
static constexpr int ROWS = 6016;          // NW*64 padded rows

// sortedBox row layout (8 floats, 32B aligned): [x1,y1,z1,x2, y2,z2,vol,score]

// ---- float <-> monotonic u32 key ----
__device__ __forceinline__ uint32_t f2u(float f) {
    uint32_t b = __float_as_uint(f);
    return b ^ ((b >> 31) ? 0xFFFFFFFFu : 0x80000000u);
}
__device__ __forceinline__ float u2f(uint32_t u) {
    uint32_t b = (u >> 31) ? (u ^ 0x80000000u) : ~u;
    return __uint_as_float(b);
}

// 1) histogram of score keys' top-16 bits (coalesced: loc innermost)
__global__ void hist_kernel(const float* __restrict__ scores_map,
                            unsigned int* __restrict__ hist) {
    int gid = blockIdx.x * blockDim.x + threadIdx.x;
    if (gid >= B_ * N_) return;
    int b = gid / N_;
    int r = gid - b * N_;
    int a = r / LOC;
    int loc = r - a * LOC;
    float sc = scores_map[((size_t)(b * 2 * A_ + A_ + a)) * LOC + loc];
    uint32_t u = f2u(sc);
    atomicAdd(&hist[b * NBIN + (u >> 16)], 1u);
}

// 2) per batch: find histogram bin where cumulative-from-top crosses PRE_NMS
__global__ void scan_kernel(const unsigned int* __restrict__ hist,
                            unsigned int* __restrict__ thr) {
    int bb = blockIdx.x;
    int t = threadIdx.x;                 // 1024 threads
    __shared__ unsigned int ssum[1024];
    const unsigned int* h = hist + (size_t)bb * NBIN;
    int base = t * 64;
    const uint4* h4 = reinterpret_cast<const uint4*>(h + base);
    unsigned int s = 0;
#pragma unroll
    for (int q = 0; q < 16; ++q) {
        uint4 v = h4[q];
        s += v.x + v.y + v.z + v.w;
    }
    ssum[t] = s;
    __syncthreads();
    for (int off = 1; off < 1024; off <<= 1) {
        unsigned int v = (t + off < 1024) ? ssum[t + off] : 0u;
        __syncthreads();
        ssum[t] += v;
        __syncthreads();
    }
    unsigned int excl = (t < 1023) ? ssum[t + 1] : 0u;
    if (excl < (unsigned)PRE_NMS && excl + s >= (unsigned)PRE_NMS) {
        unsigned int run = excl;
        for (int q = 63; q >= 0; --q) {
            run += h[base + q];
            if (run >= (unsigned)PRE_NMS) {
                thr[bb * 2 + 0] = (unsigned)(base + q);
                thr[bb * 2 + 1] = run;
                break;
            }
        }
    }
}

// 3) compact: block-aggregated atomics (1 atomicAdd per 256-thread block)
__global__ void __launch_bounds__(256) compact_kernel(
        const float* __restrict__ scores_map,
        const unsigned int* __restrict__ thr,
        unsigned long long* __restrict__ cand,
        unsigned int* __restrict__ cnt) {
    int tid = threadIdx.x;
    int gid = blockIdx.x * 256 + tid;        // grid sized exactly: no OOB
    int b = gid / N_;
    int r = gid - b * N_;
    int a = r / LOC;
    int loc = r - a * LOC;
    float sc = scores_map[((size_t)(b * 2 * A_ + A_ + a)) * LOC + loc];
    uint32_t u = f2u(sc);
    bool pass = (u >> 16) >= thr[b * 2];
    unsigned long long ball = __ballot(pass);
    int lane = tid & 63, wave = tid >> 6;
    __shared__ unsigned int wbase[4];
    if (lane == 0) wbase[wave] = (unsigned int)__popcll(ball);
    __syncthreads();
    if (tid == 0) {
        unsigned int c0 = wbase[0], c1 = wbase[1], c2 = wbase[2], c3 = wbase[3];
        unsigned int tot = c0 + c1 + c2 + c3;
        unsigned int gbase = tot ? atomicAdd(&cnt[b], tot) : 0u;
        wbase[0] = gbase;
        wbase[1] = gbase + c0;
        wbase[2] = gbase + c0 + c1;
        wbase[3] = gbase + c0 + c1 + c2;
    }
    __syncthreads();
    if (pass) {
        unsigned int pos = wbase[wave]
                         + (unsigned int)__popcll(ball & ((1ull << lane) - 1ull));
        if (pos < (unsigned)CAP) {
            int n = loc * A_ + a;   // reference flat index
            unsigned long long key = ((unsigned long long)u << 18)
                                   | (unsigned long long)(N_ - 1 - n);
            cand[(size_t)b * CAP + pos] = key;
        }
    }
}

// 4) rank-sort + decode: 64-thread blocks (2/CU via 64KB LDS), thread per candidate.
//    Keys unique -> exact rank == stable argsort order. Decodes into sortedBox[rank].
__global__ void __launch_bounds__(64) rank_decode(
        const unsigned long long* __restrict__ cand,
        const unsigned int* __restrict__ cnt,
        const float* __restrict__ bbox_frame,
        const float* __restrict__ im_info,
        const float* __restrict__ anchors,
        float* __restrict__ sortedBox) {
    __shared__ __align__(16) unsigned long long keys[CAP];   // 64 KiB
    int bb = blockIdx.y;
    int tid = threadIdx.x;
    int count = (int)cnt[bb];
    if (count > CAP) count = CAP;
    if (blockIdx.x * 64 >= count) return;    // uniform whole-block exit
    const ulonglong2* g2 = reinterpret_cast<const ulonglong2*>(cand + (size_t)bb * CAP);
    ulonglong2* s2 = reinterpret_cast<ulonglong2*>(keys);
    for (int i = tid; i < CAP / 2; i += 64) s2[i] = g2[i];
    __syncthreads();

    int i = blockIdx.x * 64 + tid;
    if (i >= count) return;
    unsigned long long me = keys[i];
    int rank = 0;
    const ulonglong2* k2 = reinterpret_cast<const ulonglong2*>(keys);
    int c2 = count >> 1;
#pragma unroll 4
    for (int j2 = 0; j2 < c2; ++j2) {
        ulonglong2 v = k2[j2];               // broadcast LDS read
        rank += (v.x > me) + (v.y > me);
    }
    if (count & 1) rank += (keys[count - 1] > me);
    if (rank >= PRE_NMS) return;

    uint32_t u = (uint32_t)(me >> 18);
    int n = N_ - 1 - (int)(me & 0x3FFFFull);
    int a = n % A_;
    int loc = n / A_;
    int k = loc % T_;
    int j = (loc / T_) % W_;
    int ii = loc / (T_ * W_);

    float ax1 = anchors[a * 6 + 0] + (float)(FEAT_STRIDE * j);
    float ay1 = anchors[a * 6 + 1] + (float)(FEAT_STRIDE * ii);
    float az1 = anchors[a * 6 + 2] + (float)k;
    float ax2 = anchors[a * 6 + 3] + (float)(FEAT_STRIDE * j);
    float ay2 = anchors[a * 6 + 4] + (float)(FEAT_STRIDE * ii);
    float az2 = anchors[a * 6 + 5] + (float)k;
    float aw = ax2 - ax1 + 1.0f, ah = ay2 - ay1 + 1.0f, al = az2 - az1 + 1.0f;
    float acx = ax1 + 0.5f * aw, acy = ay1 + 0.5f * ah, acz = az1 + 0.5f * al;

    const float* dp = bbox_frame + ((size_t)(bb * 6 * A_ + a * 6)) * LOC
                    + ii * (W_ * T_) + j * T_ + k;
    float d0 = dp[0 * LOC], d1 = dp[1 * LOC], d2 = dp[2 * LOC];
    float d3 = dp[3 * LOC], d4 = dp[4 * LOC], d5 = dp[5 * LOC];

    float pcx = d0 * aw + acx, pcy = d1 * ah + acy, pcz = d2 * al + acz;
    float pw = expf(d3) * aw, ph = expf(d4) * ah, pl = expf(d5) * al;

    float x1 = pcx - 0.5f * pw, y1 = pcy - 0.5f * ph, z1 = pcz - 0.5f * pl;
    float x2 = pcx + 0.5f * pw, y2 = pcy + 0.5f * ph, z2 = pcz + 0.5f * pl;

    float lx = im_info[1] - 1.0f, ly = im_info[0] - 1.0f, lz = im_info[2] - 1.0f;
    x1 = fminf(fmaxf(x1, 0.0f), lx); y1 = fminf(fmaxf(y1, 0.0f), ly); z1 = fminf(fmaxf(z1, 0.0f), lz);
    x2 = fminf(fmaxf(x2, 0.0f), lx); y2 = fminf(fmaxf(y2, 0.0f), ly); z2 = fminf(fmaxf(z2, 0.0f), lz);

    float vol = (x2 - x1 + 1.0f) * (y2 - y1 + 1.0f) * (z2 - z1 + 1.0f);
    float* p = sortedBox + ((size_t)bb * ROWS + rank) * 8;
    p[0] = x1; p[1] = y1; p[2] = z1; p[3] = x2;
    p[4] = y2; p[5] = z2; p[6] = vol; p[7] = u2f(u);
}

// 5) IoU bitmask: mask[bb][i][w] bit b = (j=64w+b > i) && IoU(i,j) > TH
__global__ void mask_build(const float* __restrict__ sortedBox,
                           unsigned long long* __restrict__ mask,
                           unsigned long long* __restrict__ diagArr) {
    int g = blockIdx.x / NW, w = blockIdx.x % NW;
    if (w < g) return;                      // only need upper triangle words
    int bb = blockIdx.y;
    int lane = threadIdx.x;                 // 64 threads
    __shared__ float colb[64][7];           // x1,y1,z1,x2,y2,z2,vol
    const float* sb = sortedBox + (size_t)bb * ROWS * 8;
    int col = w * 64 + lane;
    if (col < PRE_NMS) {
        const float4* cp4 = reinterpret_cast<const float4*>(sb + (size_t)col * 8);
        float4 lo = cp4[0], hi = cp4[1];
        colb[lane][0] = lo.x; colb[lane][1] = lo.y; colb[lane][2] = lo.z;
        colb[lane][3] = lo.w; colb[lane][4] = hi.x; colb[lane][5] = hi.y;
        colb[lane][6] = hi.z;
    } else {
        colb[lane][0] = 3e8f; colb[lane][1] = 0.f; colb[lane][2] = 0.f;
        colb[lane][3] = -3e8f; colb[lane][4] = 0.f; colb[lane][5] = 0.f;
        colb[lane][6] = 1.0f;
    }
    __syncthreads();
    int row = g * 64 + lane;
    if (row >= PRE_NMS) return;
    const float4* rp4 = reinterpret_cast<const float4*>(sb + (size_t)row * 8);
    float4 rlo = rp4[0], rhi = rp4[1];
    float x1 = rlo.x, y1 = rlo.y, z1 = rlo.z;
    float x2 = rlo.w, y2 = rhi.x, z2 = rhi.y, v = rhi.z;
    unsigned long long word = 0;
    for (int b2 = 0; b2 < 64; ++b2) {
        float iw = fminf(x2, colb[b2][3]) - fmaxf(x1, colb[b2][0]) + 1.0f;
        float ih = fminf(y2, colb[b2][4]) - fmaxf(y1, colb[b2][1]) + 1.0f;
        float il = fminf(z2, colb[b2][5]) - fmaxf(z1, colb[b2][2]) + 1.0f;
        iw = fmaxf(iw, 0.0f); ih = fmaxf(ih, 0.0f); il = fmaxf(il, 0.0f);
        float inter = iw * ih * il;
        float iou = inter / (v + colb[b2][6] - inter);
        int cidx = w * 64 + b2;
        if (cidx > row && iou > NMS_TH) word |= (1ull << b2);
    }
    mask[((size_t)bb * ROWS + row) * NW + w] = word;
    if (w == g) diagArr[(size_t)bb * ROWS + row] = word;
}

// 6) greedy suppress: wave0 scans survivors; 16 waves parallelize row ORs.
__global__ void __launch_bounds__(1024) suppress_kernel(
        const unsigned long long* __restrict__ mask,
        const unsigned long long* __restrict__ diagArr,
        const float* __restrict__ sortedBox,
        float* __restrict__ out) {
    int bb = blockIdx.x;
    int tid = threadIdx.x;
    int lane = tid & 63, wave = tid >> 6;
    __shared__ unsigned long long remv[NW];
    __shared__ int keptRows[64];
    __shared__ int s_nk;
    for (int i = tid; i < NW; i += 1024) remv[i] = 0ull;
    if (tid == 0) remv[NW - 1] = ~((1ull << (PRE_NMS - (NW - 1) * 64)) - 1ull);
    __syncthreads();

    const unsigned long long* M = mask + (size_t)bb * ROWS * NW;
    const unsigned long long* D = diagArr + (size_t)bb * ROWS;
    const float* sb = sortedBox + (size_t)bb * ROWS * 8;
    float* ob = out + (size_t)bb * POST_NMS * 7;

    int kept_total = 0;
    for (int c = 0; c < NW; ++c) {
        if (wave == 0) {
            unsigned long long diag = D[c * 64 + lane];        // coalesced 512B
            unsigned long long alive = ~remv[c];
            int nk = 0;
            while (alive && (kept_total + nk) < POST_NMS) {
                int b = __builtin_ctzll(alive);
                if (lane == 0) keptRows[nk] = c * 64 + b;
                ++nk;
                unsigned long long d = __shfl(diag, b);
                alive &= ~(d | (1ull << b));
            }
            if (lane == 0) s_nk = nk;
        }
        __syncthreads();
        int nk = s_nk;
        for (int w2 = c + 1 + tid; w2 < NW; w2 += 1024) {
            unsigned long long v = remv[w2];
            for (int i = 0; i < nk; ++i)
                v |= M[(size_t)keptRows[i] * NW + w2];
            remv[w2] = v;
        }
        // output rows: [score, x1,y1,z1,x2,y2,z2]; sb row: [x1..z2, vol, score]
        for (int e = tid; e < nk * 7; e += 1024) {
            int i = e / 7, j = e - i * 7;
            ob[(size_t)(kept_total + i) * 7 + j] =
                sb[(size_t)keptRows[i] * 8 + (j == 0 ? 7 : j - 1)];
        }
        kept_total += nk;
        __syncthreads();
        if (kept_total >= POST_NMS) break;
    }
    for (int idx = kept_total * 7 + tid; idx < POST_NMS * 7; idx += 1024)
        ob[idx] = 0.0f;
}

extern "C" void kernel_launch(void* const* d_in, const int* in_sizes, int n_in,
                              void* d_out, int out_size, void* d_ws, size_t ws_size,
                              hipStream_t stream) {
    const float* scores_map = (const float*)d_in[0];
    const float* bbox_frame = (const float*)d_in[1];
    const float* im_info    = (const float*)d_in[2];
    const float* anchors    = (const float*)d_in[3];
    float* out = (float*)d_out;

    // workspace layout (bytes) — ~10.09 MB
    char* ws = (char*)d_ws;
    unsigned long long* cand    = (unsigned long long*)(ws + 0);          // 131,072
    unsigned long long* mask    = (unsigned long long*)(ws + 131072);     // 9,048,064
    float* sortedBox            = (float*)(ws + 9179136);                 // 385,024
    unsigned int* hist          = (unsigned int*)(ws + 9564160);          // 524,288
    unsigned long long* diagArr = (unsigned long long*)(ws + 9564160);    // aliases hist
    unsigned int* cnt           = (unsigned int*)(ws + 10088448);         // 8
    unsigned int* thr           = (unsigned int*)(ws + 10088456);         // 16

    hipMemsetAsync(hist, 0, 524288 + 8, stream);   // hist + cnt

    int total = B_ * N_;
    hist_kernel<<<(total + 255) / 256, 256, 0, stream>>>(scores_map, hist);
    scan_kernel<<<B_, 1024, 0, stream>>>(hist, thr);
    compact_kernel<<<total / 256, 256, 0, stream>>>(scores_map, thr, cand, cnt);
    rank_decode<<<dim3(CAP / 64, B_), 64, 0, stream>>>(cand, cnt, bbox_frame,
                                                       im_info, anchors, sortedBox);
    mask_build<<<dim3(NW * NW, B_), 64, 0, stream>>>(sortedBox, mask, diagArr);
    suppress_kernel<<<B_, 1024, 0, stream>>>(mask, diagArr, sortedBox, out);
}

// Round 5
// 287.908 us; speedup vs baseline: 2.1209x; 1.0643x over previous
//
#include <hip/hip_runtime.h>
#include <stdint.h>

#define FEAT_STRIDE 16
#define PRE_NMS 6000
#define POST_NMS 300
#define NMS_TH 0.7f

static constexpr int B_ = 2, A_ = 9, H_ = 32, W_ = 32, T_ = 16;
static constexpr int LOC = H_ * W_ * T_;   // 16384
static constexpr int N_ = LOC * A_;        // 147456
static constexpr int NBIN = 65536;
static constexpr int CAP = 8192;           // candidate capacity per batch
static constexpr int NW = 94;              // ceil(6000/64) mask words per row
static constexpr int ROWS = 6016;          // NW*64 padded rows
static constexpr int CHUNK = 2048;         // rank-scan LDS chunk (16 KiB)

// sortedBox row layout (8 floats, 32B aligned): [x1,y1,z1,x2, y2,z2,vol,score]

// ---- float <-> monotonic u32 key ----
__device__ __forceinline__ uint32_t f2u(float f) {
    uint32_t b = __float_as_uint(f);
    return b ^ ((b >> 31) ? 0xFFFFFFFFu : 0x80000000u);
}
__device__ __forceinline__ float u2f(uint32_t u) {
    uint32_t b = (u >> 31) ? (u ^ 0x80000000u) : ~u;
    return __uint_as_float(b);
}

// 1) histogram of score keys' top-16 bits (coalesced: loc innermost)
__global__ void hist_kernel(const float* __restrict__ scores_map,
                            unsigned int* __restrict__ hist) {
    int gid = blockIdx.x * blockDim.x + threadIdx.x;
    if (gid >= B_ * N_) return;
    int b = gid / N_;
    int r = gid - b * N_;
    int a = r / LOC;
    int loc = r - a * LOC;
    float sc = scores_map[((size_t)(b * 2 * A_ + A_ + a)) * LOC + loc];
    uint32_t u = f2u(sc);
    atomicAdd(&hist[b * NBIN + (u >> 16)], 1u);
}

// 2) per batch: find histogram bin where cumulative-from-top crosses PRE_NMS
__global__ void scan_kernel(const unsigned int* __restrict__ hist,
                            unsigned int* __restrict__ thr) {
    int bb = blockIdx.x;
    int t = threadIdx.x;                 // 1024 threads
    __shared__ unsigned int ssum[1024];
    const unsigned int* h = hist + (size_t)bb * NBIN;
    int base = t * 64;
    const uint4* h4 = reinterpret_cast<const uint4*>(h + base);
    unsigned int s = 0;
#pragma unroll
    for (int q = 0; q < 16; ++q) {
        uint4 v = h4[q];
        s += v.x + v.y + v.z + v.w;
    }
    ssum[t] = s;
    __syncthreads();
    for (int off = 1; off < 1024; off <<= 1) {
        unsigned int v = (t + off < 1024) ? ssum[t + off] : 0u;
        __syncthreads();
        ssum[t] += v;
        __syncthreads();
    }
    unsigned int excl = (t < 1023) ? ssum[t + 1] : 0u;
    if (excl < (unsigned)PRE_NMS && excl + s >= (unsigned)PRE_NMS) {
        unsigned int run = excl;
        for (int q = 63; q >= 0; --q) {
            run += h[base + q];
            if (run >= (unsigned)PRE_NMS) {
                thr[bb * 2 + 0] = (unsigned)(base + q);
                thr[bb * 2 + 1] = run;
                break;
            }
        }
    }
}

// 3) compact: block-aggregated atomics (1 atomicAdd per 256-thread block)
__global__ void __launch_bounds__(256) compact_kernel(
        const float* __restrict__ scores_map,
        const unsigned int* __restrict__ thr,
        unsigned long long* __restrict__ cand,
        unsigned int* __restrict__ cnt) {
    int tid = threadIdx.x;
    int gid = blockIdx.x * 256 + tid;        // grid sized exactly: no OOB
    int b = gid / N_;
    int r = gid - b * N_;
    int a = r / LOC;
    int loc = r - a * LOC;
    float sc = scores_map[((size_t)(b * 2 * A_ + A_ + a)) * LOC + loc];
    uint32_t u = f2u(sc);
    bool pass = (u >> 16) >= thr[b * 2];
    unsigned long long ball = __ballot(pass);
    int lane = tid & 63, wave = tid >> 6;
    __shared__ unsigned int wbase[4];
    if (lane == 0) wbase[wave] = (unsigned int)__popcll(ball);
    __syncthreads();
    if (tid == 0) {
        unsigned int c0 = wbase[0], c1 = wbase[1], c2 = wbase[2], c3 = wbase[3];
        unsigned int tot = c0 + c1 + c2 + c3;
        unsigned int gbase = tot ? atomicAdd(&cnt[b], tot) : 0u;
        wbase[0] = gbase;
        wbase[1] = gbase + c0;
        wbase[2] = gbase + c0 + c1;
        wbase[3] = gbase + c0 + c1 + c2;
    }
    __syncthreads();
    if (pass) {
        unsigned int pos = wbase[wave]
                         + (unsigned int)__popcll(ball & ((1ull << lane) - 1ull));
        if (pos < (unsigned)CAP) {
            int n = loc * A_ + a;   // reference flat index
            unsigned long long key = ((unsigned long long)u << 18)
                                   | (unsigned long long)(N_ - 1 - n);
            cand[(size_t)b * CAP + pos] = key;
        }
    }
}

// 4) rank-sort + decode: 64-thread blocks, 2 candidates/thread (independent
//    accumulators for ILP), keys streamed through a 16 KiB LDS chunk.
//    cand[] is zero-padded past count (memset), so no staging guards needed.
//    Keys unique -> exact rank == stable argsort order.
__global__ void __launch_bounds__(64) rank_decode(
        const unsigned long long* __restrict__ cand,
        const unsigned int* __restrict__ cnt,
        const float* __restrict__ bbox_frame,
        const float* __restrict__ im_info,
        const float* __restrict__ anchors,
        float* __restrict__ sortedBox) {
    __shared__ __align__(16) unsigned long long kch[CHUNK];   // 16 KiB
    int bb = blockIdx.y;
    int tid = threadIdx.x;
    int count = (int)cnt[bb];
    if (count > CAP) count = CAP;
    int base_i = blockIdx.x * 128;
    if (base_i >= count) return;             // uniform whole-block exit
    const unsigned long long* cb = cand + (size_t)bb * CAP;
    int i0 = base_i + tid, i1 = base_i + 64 + tid;
    unsigned long long me0 = cb[i0];         // zero-padded: always safe
    unsigned long long me1 = cb[i1];
    int r0 = 0, r1 = 0;
    const ulonglong2* g2 = reinterpret_cast<const ulonglong2*>(cb);
    ulonglong2* s2 = reinterpret_cast<ulonglong2*>(kch);
    const ulonglong2* k2 = reinterpret_cast<const ulonglong2*>(kch);
    for (int cbase = 0; cbase < count; cbase += CHUNK) {
        // stage chunk (coalesced 16B loads; region zero-padded to CAP)
#pragma unroll
        for (int t = 0; t < CHUNK / 2 / 64; ++t)
            s2[t * 64 + tid] = g2[cbase / 2 + t * 64 + tid];
        __syncthreads();
#pragma unroll 8
        for (int t = 0; t < CHUNK / 2; ++t) {
            ulonglong2 v = k2[t];            // broadcast LDS read
            r0 += (v.x > me0) + (v.y > me0);
            r1 += (v.x > me1) + (v.y > me1);
        }
        __syncthreads();
    }

#pragma unroll
    for (int q = 0; q < 2; ++q) {
        int i = q ? i1 : i0;
        int rank = q ? r1 : r0;
        unsigned long long me = q ? me1 : me0;
        if (i >= count || rank >= PRE_NMS) continue;

        uint32_t u = (uint32_t)(me >> 18);
        int n = N_ - 1 - (int)(me & 0x3FFFFull);
        int a = n % A_;
        int loc = n / A_;
        int k = loc % T_;
        int j = (loc / T_) % W_;
        int ii = loc / (T_ * W_);

        float ax1 = anchors[a * 6 + 0] + (float)(FEAT_STRIDE * j);
        float ay1 = anchors[a * 6 + 1] + (float)(FEAT_STRIDE * ii);
        float az1 = anchors[a * 6 + 2] + (float)k;
        float ax2 = anchors[a * 6 + 3] + (float)(FEAT_STRIDE * j);
        float ay2 = anchors[a * 6 + 4] + (float)(FEAT_STRIDE * ii);
        float az2 = anchors[a * 6 + 5] + (float)k;
        float aw = ax2 - ax1 + 1.0f, ah = ay2 - ay1 + 1.0f, al = az2 - az1 + 1.0f;
        float acx = ax1 + 0.5f * aw, acy = ay1 + 0.5f * ah, acz = az1 + 0.5f * al;

        const float* dp = bbox_frame + ((size_t)(bb * 6 * A_ + a * 6)) * LOC
                        + ii * (W_ * T_) + j * T_ + k;
        float d0 = dp[0 * LOC], d1 = dp[1 * LOC], d2 = dp[2 * LOC];
        float d3 = dp[3 * LOC], d4 = dp[4 * LOC], d5 = dp[5 * LOC];

        float pcx = d0 * aw + acx, pcy = d1 * ah + acy, pcz = d2 * al + acz;
        float pw = expf(d3) * aw, ph = expf(d4) * ah, pl = expf(d5) * al;

        float x1 = pcx - 0.5f * pw, y1 = pcy - 0.5f * ph, z1 = pcz - 0.5f * pl;
        float x2 = pcx + 0.5f * pw, y2 = pcy + 0.5f * ph, z2 = pcz + 0.5f * pl;

        float lx = im_info[1] - 1.0f, ly = im_info[0] - 1.0f, lz = im_info[2] - 1.0f;
        x1 = fminf(fmaxf(x1, 0.0f), lx); y1 = fminf(fmaxf(y1, 0.0f), ly); z1 = fminf(fmaxf(z1, 0.0f), lz);
        x2 = fminf(fmaxf(x2, 0.0f), lx); y2 = fminf(fmaxf(y2, 0.0f), ly); z2 = fminf(fmaxf(z2, 0.0f), lz);

        float vol = (x2 - x1 + 1.0f) * (y2 - y1 + 1.0f) * (z2 - z1 + 1.0f);
        float* p = sortedBox + ((size_t)bb * ROWS + rank) * 8;
        p[0] = x1; p[1] = y1; p[2] = z1; p[3] = x2;
        p[4] = y2; p[5] = z2; p[6] = vol; p[7] = u2f(u);
    }
}

// 5) IoU bitmask: mask[bb][i][w] bit b = (j=64w+b > i) && IoU(i,j) > TH
__global__ void mask_build(const float* __restrict__ sortedBox,
                           unsigned long long* __restrict__ mask,
                           unsigned long long* __restrict__ diagArr) {
    int g = blockIdx.x / NW, w = blockIdx.x % NW;
    if (w < g) return;                      // only need upper triangle words
    int bb = blockIdx.y;
    int lane = threadIdx.x;                 // 64 threads
    __shared__ float colb[64][7];           // x1,y1,z1,x2,y2,z2,vol
    const float* sb = sortedBox + (size_t)bb * ROWS * 8;
    int col = w * 64 + lane;
    if (col < PRE_NMS) {
        const float4* cp4 = reinterpret_cast<const float4*>(sb + (size_t)col * 8);
        float4 lo = cp4[0], hi = cp4[1];
        colb[lane][0] = lo.x; colb[lane][1] = lo.y; colb[lane][2] = lo.z;
        colb[lane][3] = lo.w; colb[lane][4] = hi.x; colb[lane][5] = hi.y;
        colb[lane][6] = hi.z;
    } else {
        colb[lane][0] = 3e8f; colb[lane][1] = 0.f; colb[lane][2] = 0.f;
        colb[lane][3] = -3e8f; colb[lane][4] = 0.f; colb[lane][5] = 0.f;
        colb[lane][6] = 1.0f;
    }
    __syncthreads();
    int row = g * 64 + lane;
    if (row >= PRE_NMS) return;
    const float4* rp4 = reinterpret_cast<const float4*>(sb + (size_t)row * 8);
    float4 rlo = rp4[0], rhi = rp4[1];
    float x1 = rlo.x, y1 = rlo.y, z1 = rlo.z;
    float x2 = rlo.w, y2 = rhi.x, z2 = rhi.y, v = rhi.z;
    unsigned long long word = 0;
    for (int b2 = 0; b2 < 64; ++b2) {
        float iw = fminf(x2, colb[b2][3]) - fmaxf(x1, colb[b2][0]) + 1.0f;
        float ih = fminf(y2, colb[b2][4]) - fmaxf(y1, colb[b2][1]) + 1.0f;
        float il = fminf(z2, colb[b2][5]) - fmaxf(z1, colb[b2][2]) + 1.0f;
        iw = fmaxf(iw, 0.0f); ih = fmaxf(ih, 0.0f); il = fmaxf(il, 0.0f);
        float inter = iw * ih * il;
        float iou = inter / (v + colb[b2][6] - inter);
        int cidx = w * 64 + b2;
        if (cidx > row && iou > NMS_TH) word |= (1ull << b2);
    }
    mask[((size_t)bb * ROWS + row) * NW + w] = word;
    if (w == g) diagArr[(size_t)bb * ROWS + row] = word;
}

// 6) greedy suppress: wave0 scans survivors; 16 waves parallelize row ORs.
__global__ void __launch_bounds__(1024) suppress_kernel(
        const unsigned long long* __restrict__ mask,
        const unsigned long long* __restrict__ diagArr,
        const float* __restrict__ sortedBox,
        float* __restrict__ out) {
    int bb = blockIdx.x;
    int tid = threadIdx.x;
    int lane = tid & 63, wave = tid >> 6;
    __shared__ unsigned long long remv[NW];
    __shared__ int keptRows[64];
    __shared__ int s_nk;
    for (int i = tid; i < NW; i += 1024) remv[i] = 0ull;
    if (tid == 0) remv[NW - 1] = ~((1ull << (PRE_NMS - (NW - 1) * 64)) - 1ull);
    __syncthreads();

    const unsigned long long* M = mask + (size_t)bb * ROWS * NW;
    const unsigned long long* D = diagArr + (size_t)bb * ROWS;
    const float* sb = sortedBox + (size_t)bb * ROWS * 8;
    float* ob = out + (size_t)bb * POST_NMS * 7;

    int kept_total = 0;
    for (int c = 0; c < NW; ++c) {
        if (wave == 0) {
            unsigned long long diag = D[c * 64 + lane];        // coalesced 512B
            unsigned long long alive = ~remv[c];
            int nk = 0;
            while (alive && (kept_total + nk) < POST_NMS) {
                int b = __builtin_ctzll(alive);
                if (lane == 0) keptRows[nk] = c * 64 + b;
                ++nk;
                unsigned long long d = __shfl(diag, b);
                alive &= ~(d | (1ull << b));
            }
            if (lane == 0) s_nk = nk;
        }
        __syncthreads();
        int nk = s_nk;
        for (int w2 = c + 1 + tid; w2 < NW; w2 += 1024) {
            unsigned long long v = remv[w2];
            for (int i = 0; i < nk; ++i)
                v |= M[(size_t)keptRows[i] * NW + w2];
            remv[w2] = v;
        }
        // output rows: [score, x1,y1,z1,x2,y2,z2]; sb row: [x1..z2, vol, score]
        for (int e = tid; e < nk * 7; e += 1024) {
            int i = e / 7, j = e - i * 7;
            ob[(size_t)(kept_total + i) * 7 + j] =
                sb[(size_t)keptRows[i] * 8 + (j == 0 ? 7 : j - 1)];
        }
        kept_total += nk;
        __syncthreads();
        if (kept_total >= POST_NMS) break;
    }
    for (int idx = kept_total * 7 + tid; idx < POST_NMS * 7; idx += 1024)
        ob[idx] = 0.0f;
}

extern "C" void kernel_launch(void* const* d_in, const int* in_sizes, int n_in,
                              void* d_out, int out_size, void* d_ws, size_t ws_size,
                              hipStream_t stream) {
    const float* scores_map = (const float*)d_in[0];
    const float* bbox_frame = (const float*)d_in[1];
    const float* im_info    = (const float*)d_in[2];
    const float* anchors    = (const float*)d_in[3];
    float* out = (float*)d_out;

    // workspace layout (bytes) — total 10,088,472 (same footprint as round 3/4)
    char* ws = (char*)d_ws;
    unsigned long long* mask    = (unsigned long long*)(ws + 0);          // 9,048,064
    float* sortedBox            = (float*)(ws + 9048064);                 // 385,024
    unsigned long long* cand    = (unsigned long long*)(ws + 9433088);    // 131,072
    unsigned int* hist          = (unsigned int*)(ws + 9564160);          // 524,288
    unsigned long long* diagArr = (unsigned long long*)(ws + 9564160);    // aliases hist
                                                                          // (hist dead after scan)
    unsigned int* cnt           = (unsigned int*)(ws + 10088448);         // 8
    unsigned int* thr           = (unsigned int*)(ws + 10088456);         // 16

    // one memset: cand (zero-pad for rank scan) + hist + cnt, contiguous
    hipMemsetAsync(cand, 0, 131072 + 524288 + 8, stream);

    int total = B_ * N_;
    hist_kernel<<<(total + 255) / 256, 256, 0, stream>>>(scores_map, hist);
    scan_kernel<<<B_, 1024, 0, stream>>>(hist, thr);
    compact_kernel<<<total / 256, 256, 0, stream>>>(scores_map, thr, cand, cnt);
    rank_decode<<<dim3(CAP / 128, B_), 64, 0, stream>>>(cand, cnt, bbox_frame,
                                                        im_info, anchors, sortedBox);
    mask_build<<<dim3(NW * NW, B_), 64, 0, stream>>>(sortedBox, mask, diagArr);
    suppress_kernel<<<B_, 1024, 0, stream>>>(mask, diagArr, sortedBox, out);
}